// Round 16
// baseline (100.495 us; speedup 1.0000x reference)
//
#include <hip/hip_runtime.h>

// ChamferLoss: x,y [4, 8192, 3] fp32 -> scalar fp32.
// out = (sum_bn min_m d2 + sum_bm min_n d2) / 32768
//
// Round 20: r15 post-mortem — 4 blocks/CU regressed (43.2us, busy 57.5%,
// WRITE 20.5MB + FETCH 8.8MB = ~30MB HBM of ~1M device atomicMin RMWs).
// Busy-time invariant at ~24.8us; TLP curve minimizes at 512 blocks
// (r9: 42.5 @256, r14: ~37 @512, r15: 43.2 @1024). Tail atomics ate the
// gain. This round: 512-block config + ATOMIC-FREE epilogues — per-block
// partial mins as plain coalesced stores (rowpart[8][32768] 1MB,
// colpart[16][32768] 2MB, every slot written every iter => poison-safe,
// no memset nodes at all); sum kernel does the 8/16-way min-folds + qn +
// relu + final reduce (1024 atomicAdds total).
// Predicted: chamfer ~30-33us @ busy 72-80%, WRITE ~3.1MB, FETCH ~2.5MB;
// sum ~4us; total ~78-84us. Falsifier: chamfer ~37 w/ low WRITE =>
// in-loop per-wave stall -> shadow-reg rotation pipeline next.

#define N_      8192
#define RPB     4096          // pair-records per batch (y side)
#define FLT_BIG 3.0e38f

typedef float v2f __attribute__((ext_vector_type(2)));

__global__ void zero_out_kernel(float* out) { *out = 0.0f; }

// rotate one VGPR by 1 lane within each 16-lane row (DPP row_ror:1)
static __device__ __forceinline__ float rot16(float v) {
    return __uint_as_float((unsigned)__builtin_amdgcn_update_dpp(
        0, (int)__float_as_uint(v), 0x121, 0xf, 0xf, true));
}
static __device__ __forceinline__ v2f rot16v(v2f v) {
    v2f r; r.x = rot16(v.x); r.y = rot16(v.y); return r;
}

// one pair-record vs 4 query-pairs, BOTH directions.
// v = w_p - 2 q.p ; row keeps v (qn added at finalize);
// col needs full d2 = v + qn_q (qn uncrossed: same qnv for td and ts).
// td = {v(q0,p0), v(q1,p1)}; ts = {v(q0,p1), v(q1,p0)}.
static __device__ __forceinline__ void do_record_sym(
    v2f pxs, v2f pys, v2f pzs, v2f wv,
    const v2f* qx, const v2f* qy, const v2f* qz, const v2f* qnv,
    float* acc, v2f* cacc)
{
    #pragma unroll
    for (int j = 0; j < 4; ++j) {
        v2f td, ts;
        asm("v_pk_fma_f32 %0, %1, %2, %3"
            : "=v"(td) : "v"(qz[j]), "v"(pzs), "v"(wv));
        asm("v_pk_fma_f32 %0, %1, %2, %3 op_sel:[0,1,1] op_sel_hi:[1,0,0]"
            : "=v"(ts) : "v"(qz[j]), "v"(pzs), "v"(wv));
        asm("v_pk_fma_f32 %0, %1, %2, %0"
            : "+v"(td) : "v"(qy[j]), "v"(pys));
        asm("v_pk_fma_f32 %0, %1, %2, %0 op_sel:[0,1,0] op_sel_hi:[1,0,1]"
            : "+v"(ts) : "v"(qy[j]), "v"(pys));
        asm("v_pk_fma_f32 %0, %1, %2, %0"
            : "+v"(td) : "v"(qx[j]), "v"(pxs));
        asm("v_pk_fma_f32 %0, %1, %2, %0 op_sel:[0,1,0] op_sel_hi:[1,0,1]"
            : "+v"(ts) : "v"(qx[j]), "v"(pxs));
        // row mins (x-queries), qn excluded
        asm("v_min3_f32 %0, %0, %1, %2" : "+v"(acc[2*j])   : "v"(td.x), "v"(ts.x));
        asm("v_min3_f32 %0, %0, %1, %2" : "+v"(acc[2*j+1]) : "v"(td.y), "v"(ts.y));
        // col mins (y-points), full d2: + qn (uncrossed; p0 cells are td.x,ts.y)
        v2f tdq, tsq;
        asm("v_pk_add_f32 %0, %1, %2" : "=v"(tdq) : "v"(td), "v"(qnv[j]));
        asm("v_pk_add_f32 %0, %1, %2" : "=v"(tsq) : "v"(ts), "v"(qnv[j]));
        asm("v_min3_f32 %0, %0, %1, %2" : "+v"(cacc->x) : "v"(tdq.x), "v"(tsq.y));
        asm("v_min3_f32 %0, %0, %1, %2" : "+v"(cacc->y) : "v"(tsq.x), "v"(tdq.y));
    }
}

// 512 blocks x 512 thr (8 waves), 2 blocks/CU (4 waves/SIMD). Block =
// (batch, qgroup of 512 x-queries, seg of 512 y-records). Wave sweeps 64
// records = 4 ring-fills of 16; each unique cell feeds both directions.
// Epilogues: plain coalesced partial stores, NO atomics.
__global__ __launch_bounds__(512, 4) void chamfer_kernel(
    const float* __restrict__ xraw, const float* __restrict__ yraw,
    float* __restrict__ rowpart,        // [8 seg][32768 gq]
    float* __restrict__ colpart,        // [16 qg][32768 gpoint]
    float* __restrict__ out)
{
    __shared__ float red[8 * 512];      // 16 KB (row combine)
    __shared__ float colbuf[8][128];    // 4 KB  (per-wave col mins)

    const int tid  = threadIdx.x;
    const int lane = tid & 63;
    const int wave = __builtin_amdgcn_readfirstlane(tid >> 6);
    const int blk  = blockIdx.x;        // 0..511
    const int batch = blk >> 7;
    const int qg    = (blk >> 3) & 15;
    const int seg   = blk & 7;

    if (blk == 0 && tid == 0) *out = 0.0f;   // sum kernel accumulates later

    // ---- load this lane's 8 x-queries (24 floats, 16B-aligned) ----
    const int qbase = batch * N_ + qg * 512;
    float f[24];
    {
        const float4* qv = (const float4*)(xraw + (size_t)qbase * 3) + lane * 6;
        #pragma unroll
        for (int k = 0; k < 6; ++k) {
            float4 t = qv[k];
            f[4*k] = t.x; f[4*k+1] = t.y; f[4*k+2] = t.z; f[4*k+3] = t.w;
        }
    }
    v2f qx[4], qy[4], qz[4], qnv[4];
    float acc[8];
    #pragma unroll
    for (int j = 0; j < 4; ++j) {
        qnv[j].x = fmaf(f[6*j+0], f[6*j+0],
                   fmaf(f[6*j+1], f[6*j+1], f[6*j+2] * f[6*j+2]));
        qnv[j].y = fmaf(f[6*j+3], f[6*j+3],
                   fmaf(f[6*j+4], f[6*j+4], f[6*j+5] * f[6*j+5]));
        qx[j] = (v2f){-2.0f * f[6*j+0], -2.0f * f[6*j+3]};
        qy[j] = (v2f){-2.0f * f[6*j+1], -2.0f * f[6*j+4]};
        qz[j] = (v2f){-2.0f * f[6*j+2], -2.0f * f[6*j+5]};
        acc[2*j] = FLT_BIG; acc[2*j+1] = FLT_BIG;
    }

    // ---- symmetric systolic sweep: 64 y-records = 4 ring-fills of 16 ----
    const int rbase = seg * 512 + wave * 64;      // wave's record base in batch
    const float2* rp = (const float2*)
        (yraw + (size_t)(batch * RPB + rbase + (lane & 15)) * 6);
    float2 A = rp[0], Bv = rp[1], Cv = rp[2];
    #pragma unroll 1
    for (int fl = 0; fl < 4; ++fl) {
        v2f pxs = (v2f){A.x,  Bv.y};
        v2f pys = (v2f){A.y,  Cv.x};
        v2f pzs = (v2f){Bv.x, Cv.y};
        v2f wv;
        wv.x = fmaf(A.x,  A.x,  fmaf(A.y,  A.y,  Bv.x * Bv.x));
        wv.y = fmaf(Bv.y, Bv.y, fmaf(Cv.x, Cv.x, Cv.y * Cv.y));
        if (fl < 3) {                    // prefetch next fill (16 recs = 48 float2)
            const float2* np = rp + (fl + 1) * 48;
            A = np[0]; Bv = np[1]; Cv = np[2];
        }
        v2f cacc = (v2f){FLT_BIG, FLT_BIG};
        #pragma unroll
        for (int s = 0; s < 16; ++s) {
            if (s) {
                pxs = rot16v(pxs); pys = rot16v(pys);
                pzs = rot16v(pzs); wv  = rot16v(wv);
                cacc = rot16v(cacc);     // col acc rides its record
            }
            do_record_sym(pxs, pys, pzs, wv, qx, qy, qz, qnv, acc, &cacc);
        }
        // 15 rotations happened; one more returns cacc to its record's
        // home lane (16 == identity, valid for either ror direction).
        cacc = rot16v(cacc);
        // fold the 4 duplicate rows, relu, stash in LDS.
        cacc.x = fminf(cacc.x, __shfl_xor(cacc.x, 16));
        cacc.x = fminf(cacc.x, __shfl_xor(cacc.x, 32));
        cacc.y = fminf(cacc.y, __shfl_xor(cacc.y, 16));
        cacc.y = fminf(cacc.y, __shfl_xor(cacc.y, 32));
        if (lane < 16) {
            colbuf[wave][fl * 32 + lane * 2]     = fmaxf(0.0f, cacc.x);
            colbuf[wave][fl * 32 + lane * 2 + 1] = fmaxf(0.0f, cacc.y);
        }
    }

    // ---- col epilogue: wave's 128 relu'd col-mins -> plain float2 store ----
    {
        float2* cp = (float2*)(colpart + (size_t)qg * 32768 + batch * N_ + 2 * rbase);
        float2 v = ((const float2*)colbuf[wave])[lane];   // 0..63 -> 128 floats
        cp[lane] = v;
    }

    // ---- row epilogue: block combine -> plain store (qn/relu deferred) ----
    #pragma unroll
    for (int j = 0; j < 8; ++j) red[wave * 512 + lane * 8 + j] = acc[j];
    __syncthreads();
    float m = red[tid];                          // thread t owns query qbase+t
    #pragma unroll
    for (int w = 1; w < 8; ++w) m = fminf(m, red[w * 512 + tid]);
    rowpart[(size_t)seg * 32768 + qbase + tid] = m;
}

// ---------------- phase 2: fold partials -> scalar ----------------
// 128 blocks x 512: blocks 0..63 = x side (fold 8 segs + qn + relu),
// blocks 64..127 = y side (fold 16 qgs; already relu'd).
__global__ __launch_bounds__(512) void sum_kernel(
    const float* __restrict__ xraw,
    const float* __restrict__ rowpart, const float* __restrict__ colpart,
    float* __restrict__ out)
{
    const int b   = blockIdx.x;
    const int tid = threadIdx.x;
    float d2;
    if (b < 64) {
        int gq = b * 512 + tid;                  // x-query 0..32767
        float m = rowpart[gq];
        #pragma unroll
        for (int s = 1; s < 8; ++s) m = fminf(m, rowpart[(size_t)s * 32768 + gq]);
        float ax = xraw[gq*3+0], ay = xraw[gq*3+1], az = xraw[gq*3+2];
        float qn = fmaf(ax, ax, fmaf(ay, ay, az * az));
        d2 = fmaxf(0.0f, qn + m);
    } else {
        int gp = (b - 64) * 512 + tid;           // y-point 0..32767
        float m = colpart[gp];
        #pragma unroll
        for (int q = 1; q < 16; ++q) m = fminf(m, colpart[(size_t)q * 32768 + gp]);
        d2 = m;                                  // relu(min) == min(relu'd)
    }
    #pragma unroll
    for (int off = 32; off > 0; off >>= 1) d2 += __shfl_xor(d2, off);
    if ((tid & 63) == 0) atomicAdd(out, d2 * (1.0f / 32768.0f));
}

// ---------------- fallback (ws too small): round-1 kernel ----------------
__global__ __launch_bounds__(1024) void chamfer_raw_kernel(
    const float* __restrict__ xraw, const float* __restrict__ yraw,
    float* __restrict__ out)
{
    __shared__ float4 red4[16][64];
    const int tid  = threadIdx.x;
    const int wave = tid >> 6;
    const int lane = tid & 63;
    const int blk  = blockIdx.x;
    const bool xdir = (blk < 128);
    const int b    = (blk & 127) >> 5;
    const int qofs = (blk & 31) << 8;
    const float* qraw = xdir ? xraw : yraw;
    const float* oraw = xdir ? yraw : xraw;
    float qx0[4], qx1[4], qx2[4], acc[4];
    #pragma unroll
    for (int q = 0; q < 4; ++q) {
        int gq = b * N_ + qofs + lane*4 + q;
        qx0[q] = qraw[gq*3+0]; qx1[q] = qraw[gq*3+1]; qx2[q] = qraw[gq*3+2];
        acc[q] = FLT_BIG;
    }
    const float* opp = oraw + (size_t)(b * N_ + wave * 512) * 3;
    #pragma unroll 4
    for (int k = 0; k < 512; ++k) {
        float p0 = opp[k*3+0], p1 = opp[k*3+1], p2 = opp[k*3+2];
        float w  = fmaf(p0, p0, fmaf(p1, p1, p2*p2));
        #pragma unroll
        for (int q = 0; q < 4; ++q) {
            float dot = qx0[q]*p0 + qx1[q]*p1 + qx2[q]*p2;
            acc[q] = fminf(acc[q], fmaf(-2.0f, dot, w));
        }
    }
    red4[wave][lane] = make_float4(acc[0], acc[1], acc[2], acc[3]);
    __syncthreads();
    if (tid < 256) {
        const float* red = (const float*)red4;
        float m = red[tid];
        #pragma unroll
        for (int w = 1; w < 16; ++w) m = fminf(m, red[w*256 + tid]);
        int gq = b * N_ + qofs + tid;
        float ax = qraw[gq*3+0], ay = qraw[gq*3+1], az = qraw[gq*3+2];
        float d2 = fmaxf(0.0f, fmaf(ax,ax,fmaf(ay,ay,az*az)) + m);
        #pragma unroll
        for (int off = 32; off > 0; off >>= 1) d2 += __shfl_xor(d2, off);
        if ((tid & 63) == 0) atomicAdd(out, d2 * (1.0f / 32768.0f));
    }
}

extern "C" void kernel_launch(void* const* d_in, const int* in_sizes, int n_in,
                              void* d_out, int out_size, void* d_ws, size_t ws_size,
                              hipStream_t stream)
{
    const float* x = (const float*)d_in[0];
    const float* y = (const float*)d_in[1];
    float* out = (float*)d_out;

    // ws layout: rowpart [8][32768] f32 (1MB), colpart [16][32768] f32 (2MB)
    const size_t need = (size_t)(8 + 16) * 32768 * sizeof(float);
    if (ws_size >= need) {
        float* rowpart = (float*)d_ws;
        float* colpart = rowpart + (size_t)8 * 32768;
        chamfer_kernel<<<512, 512, 0, stream>>>(x, y, rowpart, colpart, out);
        sum_kernel<<<128, 512, 0, stream>>>(x, rowpart, colpart, out);
    } else {
        zero_out_kernel<<<1, 1, 0, stream>>>(out);
        chamfer_raw_kernel<<<256, 1024, 0, stream>>>(x, y, out);
    }
}

// Round 17
// 93.250 us; speedup vs baseline: 1.0777x; 1.0777x over previous
//
#include <hip/hip_runtime.h>

// ChamferLoss: x,y [4, 8192, 3] fp32 -> scalar fp32.
// out = (sum_bn min_m d2 + sum_bm min_n d2) / 32768
//
// Round 21: REVERT to r14's verified-best configuration (92.55us total).
// r16 post-mortem: atomic-free partial-store restructure regressed to
// 100.5us — budget closes only if the new 128-block fold kernel costs
// ~13-15us vs the ~2us sum it replaced; r14's ~327K atomics were already
// tail-hidden. Also resolved: the paired fill PMC rows are ONE 268MB
// 40us harness poison per iteration (two TCC counter passes), 84% HBM —
// memory-roofline on its own, untouchable.
// Session accounting at this config: 40.3 fill + ~38-40 chamfer (24us
// invariant VALU floor + ~15 stall that survived 6 structural attacks)
// + ~2 sum + ~0.3 memsets + ~10 dispatch gaps = 92.5. Remaining deltas
// (<8us) are below combined measurement floor (chamfer hidden under the
// fill; totals +-1.5). If this confirms ~92.5, declare roofline.

#define N_      8192
#define RPB     4096          // pair-records per batch (y side)
#define FLT_BIG 3.0e38f

typedef float v2f __attribute__((ext_vector_type(2)));

__global__ void zero_out_kernel(float* out) { *out = 0.0f; }

// rotate one VGPR by 1 lane within each 16-lane row (DPP row_ror:1)
static __device__ __forceinline__ float rot16(float v) {
    return __uint_as_float((unsigned)__builtin_amdgcn_update_dpp(
        0, (int)__float_as_uint(v), 0x121, 0xf, 0xf, true));
}
static __device__ __forceinline__ v2f rot16v(v2f v) {
    v2f r; r.x = rot16(v.x); r.y = rot16(v.y); return r;
}

// one pair-record vs 4 query-pairs, BOTH directions.
// v = w_p - 2 q.p ; row keeps v (qn added in epilogue);
// col needs full d2 = v + qn_q (qn uncrossed: same qnv for td and ts).
// td = {v(q0,p0), v(q1,p1)}; ts = {v(q0,p1), v(q1,p0)}.
static __device__ __forceinline__ void do_record_sym(
    v2f pxs, v2f pys, v2f pzs, v2f wv,
    const v2f* qx, const v2f* qy, const v2f* qz, const v2f* qnv,
    float* acc, v2f* cacc)
{
    #pragma unroll
    for (int j = 0; j < 4; ++j) {
        v2f td, ts;
        asm("v_pk_fma_f32 %0, %1, %2, %3"
            : "=v"(td) : "v"(qz[j]), "v"(pzs), "v"(wv));
        asm("v_pk_fma_f32 %0, %1, %2, %3 op_sel:[0,1,1] op_sel_hi:[1,0,0]"
            : "=v"(ts) : "v"(qz[j]), "v"(pzs), "v"(wv));
        asm("v_pk_fma_f32 %0, %1, %2, %0"
            : "+v"(td) : "v"(qy[j]), "v"(pys));
        asm("v_pk_fma_f32 %0, %1, %2, %0 op_sel:[0,1,0] op_sel_hi:[1,0,1]"
            : "+v"(ts) : "v"(qy[j]), "v"(pys));
        asm("v_pk_fma_f32 %0, %1, %2, %0"
            : "+v"(td) : "v"(qx[j]), "v"(pxs));
        asm("v_pk_fma_f32 %0, %1, %2, %0 op_sel:[0,1,0] op_sel_hi:[1,0,1]"
            : "+v"(ts) : "v"(qx[j]), "v"(pxs));
        // row mins (x-queries), qn excluded
        asm("v_min3_f32 %0, %0, %1, %2" : "+v"(acc[2*j])   : "v"(td.x), "v"(ts.x));
        asm("v_min3_f32 %0, %0, %1, %2" : "+v"(acc[2*j+1]) : "v"(td.y), "v"(ts.y));
        // col mins (y-points), full d2: + qn (uncrossed; p0 cells are td.x,ts.y)
        v2f tdq, tsq;
        asm("v_pk_add_f32 %0, %1, %2" : "=v"(tdq) : "v"(td), "v"(qnv[j]));
        asm("v_pk_add_f32 %0, %1, %2" : "=v"(tsq) : "v"(ts), "v"(qnv[j]));
        asm("v_min3_f32 %0, %0, %1, %2" : "+v"(cacc->x) : "v"(tdq.x), "v"(tsq.y));
        asm("v_min3_f32 %0, %0, %1, %2" : "+v"(cacc->y) : "v"(tsq.x), "v"(tdq.y));
    }
}

// 512 blocks x 512 thr (8 waves), 2 blocks/CU (4 waves/SIMD). Block =
// (batch, qgroup of 512 x-queries, seg of 512 y-records). Wave sweeps 64
// records = 4 ring-fills of 16; each unique cell feeds both directions.
__global__ __launch_bounds__(512, 4) void chamfer_kernel(
    const float* __restrict__ xraw, const float* __restrict__ yraw,
    unsigned int* __restrict__ pmin)    // [2][4][8192]: x-side then y-side
{
    __shared__ float red[8 * 512];      // 16 KB (row combine)
    __shared__ float colbuf[8][128];    // 4 KB  (per-wave col mins)

    const int tid  = threadIdx.x;
    const int lane = tid & 63;
    const int wave = __builtin_amdgcn_readfirstlane(tid >> 6);
    const int blk  = blockIdx.x;        // 0..511
    const int batch = blk >> 7;
    const int qg    = (blk >> 3) & 15;
    const int seg   = blk & 7;

    // ---- load this lane's 8 x-queries (24 floats, 16B-aligned) ----
    const int qbase = batch * N_ + qg * 512;
    float f[24];
    {
        const float4* qv = (const float4*)(xraw + (size_t)qbase * 3) + lane * 6;
        #pragma unroll
        for (int k = 0; k < 6; ++k) {
            float4 t = qv[k];
            f[4*k] = t.x; f[4*k+1] = t.y; f[4*k+2] = t.z; f[4*k+3] = t.w;
        }
    }
    v2f qx[4], qy[4], qz[4], qnv[4];
    float acc[8];
    #pragma unroll
    for (int j = 0; j < 4; ++j) {
        qnv[j].x = fmaf(f[6*j+0], f[6*j+0],
                   fmaf(f[6*j+1], f[6*j+1], f[6*j+2] * f[6*j+2]));
        qnv[j].y = fmaf(f[6*j+3], f[6*j+3],
                   fmaf(f[6*j+4], f[6*j+4], f[6*j+5] * f[6*j+5]));
        qx[j] = (v2f){-2.0f * f[6*j+0], -2.0f * f[6*j+3]};
        qy[j] = (v2f){-2.0f * f[6*j+1], -2.0f * f[6*j+4]};
        qz[j] = (v2f){-2.0f * f[6*j+2], -2.0f * f[6*j+5]};
        acc[2*j] = FLT_BIG; acc[2*j+1] = FLT_BIG;
    }

    // ---- symmetric systolic sweep: 64 y-records = 4 ring-fills of 16 ----
    const int rbase = seg * 512 + wave * 64;      // wave's record base in batch
    const float2* rp = (const float2*)
        (yraw + (size_t)(batch * RPB + rbase + (lane & 15)) * 6);
    float2 A = rp[0], Bv = rp[1], Cv = rp[2];
    #pragma unroll 1
    for (int fl = 0; fl < 4; ++fl) {
        v2f pxs = (v2f){A.x,  Bv.y};
        v2f pys = (v2f){A.y,  Cv.x};
        v2f pzs = (v2f){Bv.x, Cv.y};
        v2f wv;
        wv.x = fmaf(A.x,  A.x,  fmaf(A.y,  A.y,  Bv.x * Bv.x));
        wv.y = fmaf(Bv.y, Bv.y, fmaf(Cv.x, Cv.x, Cv.y * Cv.y));
        if (fl < 3) {                    // prefetch next fill (16 recs = 48 float2)
            const float2* np = rp + (fl + 1) * 48;
            A = np[0]; Bv = np[1]; Cv = np[2];
        }
        v2f cacc = (v2f){FLT_BIG, FLT_BIG};
        #pragma unroll
        for (int s = 0; s < 16; ++s) {
            if (s) {
                pxs = rot16v(pxs); pys = rot16v(pys);
                pzs = rot16v(pzs); wv  = rot16v(wv);
                cacc = rot16v(cacc);     // col acc rides its record
            }
            do_record_sym(pxs, pys, pzs, wv, qx, qy, qz, qnv, acc, &cacc);
        }
        // 15 rotations happened; one more returns cacc to its record's
        // home lane (16 == identity, valid for either ror direction).
        cacc = rot16v(cacc);
        // fold the 4 duplicate rows, relu, stash in LDS.
        cacc.x = fminf(cacc.x, __shfl_xor(cacc.x, 16));
        cacc.x = fminf(cacc.x, __shfl_xor(cacc.x, 32));
        cacc.y = fminf(cacc.y, __shfl_xor(cacc.y, 16));
        cacc.y = fminf(cacc.y, __shfl_xor(cacc.y, 32));
        if (lane < 16) {
            colbuf[wave][fl * 32 + lane * 2]     = fmaxf(0.0f, cacc.x);
            colbuf[wave][fl * 32 + lane * 2 + 1] = fmaxf(0.0f, cacc.y);
        }
    }

    // ---- col epilogue: wave's 128 col-mins -> global atomicMin ----
    {
        unsigned int* py = pmin + 32768 + batch * N_ + 2 * rbase;
        #pragma unroll
        for (int k = 0; k < 2; ++k) {
            int idx = lane * 2 + k;              // 0..127
            float v = colbuf[wave][idx];
            atomicMin(&py[idx], __float_as_uint(v));
        }
    }

    // ---- row epilogue: block combine + relu(qn+min) -> atomicMin ----
    #pragma unroll
    for (int j = 0; j < 8; ++j) red[wave * 512 + lane * 8 + j] = acc[j];
    __syncthreads();
    float m = red[tid];                          // thread t owns query qbase+t
    #pragma unroll
    for (int w = 1; w < 8; ++w) m = fminf(m, red[w * 512 + tid]);
    int gq = qbase + tid;
    float ax = xraw[gq*3+0], ay = xraw[gq*3+1], az = xraw[gq*3+2];
    float qn = fmaf(ax, ax, fmaf(ay, ay, az * az));
    float d2 = fmaxf(0.0f, qn + m);              // relu commutes with min
    atomicMin(&pmin[gq], __float_as_uint(d2));
}

// ---------------- phase 2: sum 65536 per-point d2 -> scalar ----------------
__global__ __launch_bounds__(256) void sum_kernel(
    const unsigned int* __restrict__ pmin, float* __restrict__ out)
{
    int i = blockIdx.x * 256 + threadIdx.x;   // 0..16383, 4 values each
    float4 v = ((const float4*)pmin)[i];      // bits are valid non-neg floats
    float s = v.x + v.y + v.z + v.w;
    #pragma unroll
    for (int off = 32; off > 0; off >>= 1) s += __shfl_xor(s, off);
    if ((threadIdx.x & 63) == 0) atomicAdd(out, s * (1.0f / 32768.0f));
}

// ---------------- fallback (ws too small): round-1 kernel ----------------
__global__ __launch_bounds__(1024) void chamfer_raw_kernel(
    const float* __restrict__ xraw, const float* __restrict__ yraw,
    float* __restrict__ out)
{
    __shared__ float4 red4[16][64];
    const int tid  = threadIdx.x;
    const int wave = tid >> 6;
    const int lane = tid & 63;
    const int blk  = blockIdx.x;
    const bool xdir = (blk < 128);
    const int b    = (blk & 127) >> 5;
    const int qofs = (blk & 31) << 8;
    const float* qraw = xdir ? xraw : yraw;
    const float* oraw = xdir ? yraw : xraw;
    float qx0[4], qx1[4], qx2[4], acc[4];
    #pragma unroll
    for (int q = 0; q < 4; ++q) {
        int gq = b * N_ + qofs + lane*4 + q;
        qx0[q] = qraw[gq*3+0]; qx1[q] = qraw[gq*3+1]; qx2[q] = qraw[gq*3+2];
        acc[q] = FLT_BIG;
    }
    const float* opp = oraw + (size_t)(b * N_ + wave * 512) * 3;
    #pragma unroll 4
    for (int k = 0; k < 512; ++k) {
        float p0 = opp[k*3+0], p1 = opp[k*3+1], p2 = opp[k*3+2];
        float w  = fmaf(p0, p0, fmaf(p1, p1, p2*p2));
        #pragma unroll
        for (int q = 0; q < 4; ++q) {
            float dot = qx0[q]*p0 + qx1[q]*p1 + qx2[q]*p2;
            acc[q] = fminf(acc[q], fmaf(-2.0f, dot, w));
        }
    }
    red4[wave][lane] = make_float4(acc[0], acc[1], acc[2], acc[3]);
    __syncthreads();
    if (tid < 256) {
        const float* red = (const float*)red4;
        float m = red[tid];
        #pragma unroll
        for (int w = 1; w < 16; ++w) m = fminf(m, red[w*256 + tid]);
        int gq = b * N_ + qofs + tid;
        float ax = qraw[gq*3+0], ay = qraw[gq*3+1], az = qraw[gq*3+2];
        float d2 = fmaxf(0.0f, fmaf(ax,ax,fmaf(ay,ay,az*az)) + m);
        #pragma unroll
        for (int off = 32; off > 0; off >>= 1) d2 += __shfl_xor(d2, off);
        if ((tid & 63) == 0) atomicAdd(out, d2 * (1.0f / 32768.0f));
    }
}

extern "C" void kernel_launch(void* const* d_in, const int* in_sizes, int n_in,
                              void* d_out, int out_size, void* d_ws, size_t ws_size,
                              hipStream_t stream)
{
    const float* x = (const float*)d_in[0];
    const float* y = (const float*)d_in[1];
    float* out = (float*)d_out;

    // ws layout: pmin uint[65536] = 256 KB
    const size_t need = (size_t)65536 * 4;
    if (ws_size >= need) {
        unsigned int* pmin = (unsigned int*)d_ws;
        hipMemsetAsync(pmin, 0xFF, need, stream);   // uint-min identity
        hipMemsetAsync(out, 0, 4, stream);
        chamfer_kernel<<<512, 512, 0, stream>>>(x, y, pmin);
        sum_kernel<<<64, 256, 0, stream>>>(pmin, out);
    } else {
        zero_out_kernel<<<1, 1, 0, stream>>>(out);
        chamfer_raw_kernel<<<256, 1024, 0, stream>>>(x, y, out);
    }
}

// Round 18
// 93.246 us; speedup vs baseline: 1.0777x; 1.0000x over previous
//
#include <hip/hip_runtime.h>

// ChamferLoss: x,y [4, 8192, 3] fp32 -> scalar fp32.
// out = (sum_bn min_m d2 + sum_bm min_n d2) / 32768
//
// Round 22: r17 confirmed the revert (93.25 vs 92.55, within noise).
// Accounting: 40.1 fill (harness poison, 84% HBM) + ~38-40 chamfer
// (24-25us invariant busy + ~14us stall) + ~2 sum + ~10 gaps.
// Before declaring roofline: the ~35% chamfer stall has never been
// attacked at the INTRA-WAVE ILP level — all six prior attacks were
// delivery/occupancy/tail. The in-place ring rotation (pxs=rot(pxs))
// serializes each step: next rotations wait on all consumers (WAR) and
// consumers wait on rotations (DPP->VALU + VALU->DPP hazards).
// This round: explicit shadow-register pipeline — pre-rotate ring into
// fresh regs at step top (independent of this step's 40 consumers, so
// the scheduler interleaves), consume current, swap. cacc still
// rotate-after-update (carries the step's min3 result); 16 in-loop
// rotations == identity, post-loop rotation removed. Same math; +8 VGPR.
// Predicted: chamfer ~30-33us, total 84-88. Pre-committed falsifier:
// total 92-94 => stall not source-addressable; declare roofline
// (40 fill + 24 VALU floor + 14 irreducible stall + 12 dispatch).

#define N_      8192
#define RPB     4096          // pair-records per batch (y side)
#define FLT_BIG 3.0e38f

typedef float v2f __attribute__((ext_vector_type(2)));

__global__ void zero_out_kernel(float* out) { *out = 0.0f; }

// rotate one VGPR by 1 lane within each 16-lane row (DPP row_ror:1)
static __device__ __forceinline__ float rot16(float v) {
    return __uint_as_float((unsigned)__builtin_amdgcn_update_dpp(
        0, (int)__float_as_uint(v), 0x121, 0xf, 0xf, true));
}
static __device__ __forceinline__ v2f rot16v(v2f v) {
    v2f r; r.x = rot16(v.x); r.y = rot16(v.y); return r;
}

// one pair-record vs 4 query-pairs, BOTH directions.
// v = w_p - 2 q.p ; row keeps v (qn added in epilogue);
// col needs full d2 = v + qn_q (qn uncrossed: same qnv for td and ts).
// td = {v(q0,p0), v(q1,p1)}; ts = {v(q0,p1), v(q1,p0)}.
static __device__ __forceinline__ void do_record_sym(
    v2f pxs, v2f pys, v2f pzs, v2f wv,
    const v2f* qx, const v2f* qy, const v2f* qz, const v2f* qnv,
    float* acc, v2f* cacc)
{
    #pragma unroll
    for (int j = 0; j < 4; ++j) {
        v2f td, ts;
        asm("v_pk_fma_f32 %0, %1, %2, %3"
            : "=v"(td) : "v"(qz[j]), "v"(pzs), "v"(wv));
        asm("v_pk_fma_f32 %0, %1, %2, %3 op_sel:[0,1,1] op_sel_hi:[1,0,0]"
            : "=v"(ts) : "v"(qz[j]), "v"(pzs), "v"(wv));
        asm("v_pk_fma_f32 %0, %1, %2, %0"
            : "+v"(td) : "v"(qy[j]), "v"(pys));
        asm("v_pk_fma_f32 %0, %1, %2, %0 op_sel:[0,1,0] op_sel_hi:[1,0,1]"
            : "+v"(ts) : "v"(qy[j]), "v"(pys));
        asm("v_pk_fma_f32 %0, %1, %2, %0"
            : "+v"(td) : "v"(qx[j]), "v"(pxs));
        asm("v_pk_fma_f32 %0, %1, %2, %0 op_sel:[0,1,0] op_sel_hi:[1,0,1]"
            : "+v"(ts) : "v"(qx[j]), "v"(pxs));
        // row mins (x-queries), qn excluded
        asm("v_min3_f32 %0, %0, %1, %2" : "+v"(acc[2*j])   : "v"(td.x), "v"(ts.x));
        asm("v_min3_f32 %0, %0, %1, %2" : "+v"(acc[2*j+1]) : "v"(td.y), "v"(ts.y));
        // col mins (y-points), full d2: + qn (uncrossed; p0 cells are td.x,ts.y)
        v2f tdq, tsq;
        asm("v_pk_add_f32 %0, %1, %2" : "=v"(tdq) : "v"(td), "v"(qnv[j]));
        asm("v_pk_add_f32 %0, %1, %2" : "=v"(tsq) : "v"(ts), "v"(qnv[j]));
        asm("v_min3_f32 %0, %0, %1, %2" : "+v"(cacc->x) : "v"(tdq.x), "v"(tsq.y));
        asm("v_min3_f32 %0, %0, %1, %2" : "+v"(cacc->y) : "v"(tsq.x), "v"(tdq.y));
    }
}

// 512 blocks x 512 thr (8 waves), 2 blocks/CU (4 waves/SIMD). Block =
// (batch, qgroup of 512 x-queries, seg of 512 y-records). Wave sweeps 64
// records = 4 ring-fills of 16; each unique cell feeds both directions.
__global__ __launch_bounds__(512, 4) void chamfer_kernel(
    const float* __restrict__ xraw, const float* __restrict__ yraw,
    unsigned int* __restrict__ pmin)    // [2][4][8192]: x-side then y-side
{
    __shared__ float red[8 * 512];      // 16 KB (row combine)
    __shared__ float colbuf[8][128];    // 4 KB  (per-wave col mins)

    const int tid  = threadIdx.x;
    const int lane = tid & 63;
    const int wave = __builtin_amdgcn_readfirstlane(tid >> 6);
    const int blk  = blockIdx.x;        // 0..511
    const int batch = blk >> 7;
    const int qg    = (blk >> 3) & 15;
    const int seg   = blk & 7;

    // ---- load this lane's 8 x-queries (24 floats, 16B-aligned) ----
    const int qbase = batch * N_ + qg * 512;
    float f[24];
    {
        const float4* qv = (const float4*)(xraw + (size_t)qbase * 3) + lane * 6;
        #pragma unroll
        for (int k = 0; k < 6; ++k) {
            float4 t = qv[k];
            f[4*k] = t.x; f[4*k+1] = t.y; f[4*k+2] = t.z; f[4*k+3] = t.w;
        }
    }
    v2f qx[4], qy[4], qz[4], qnv[4];
    float acc[8];
    #pragma unroll
    for (int j = 0; j < 4; ++j) {
        qnv[j].x = fmaf(f[6*j+0], f[6*j+0],
                   fmaf(f[6*j+1], f[6*j+1], f[6*j+2] * f[6*j+2]));
        qnv[j].y = fmaf(f[6*j+3], f[6*j+3],
                   fmaf(f[6*j+4], f[6*j+4], f[6*j+5] * f[6*j+5]));
        qx[j] = (v2f){-2.0f * f[6*j+0], -2.0f * f[6*j+3]};
        qy[j] = (v2f){-2.0f * f[6*j+1], -2.0f * f[6*j+4]};
        qz[j] = (v2f){-2.0f * f[6*j+2], -2.0f * f[6*j+5]};
        acc[2*j] = FLT_BIG; acc[2*j+1] = FLT_BIG;
    }

    // ---- symmetric systolic sweep: 64 y-records = 4 ring-fills of 16,
    //      shadow-register pipelined rotation ----
    const int rbase = seg * 512 + wave * 64;      // wave's record base in batch
    const float2* rp = (const float2*)
        (yraw + (size_t)(batch * RPB + rbase + (lane & 15)) * 6);
    float2 A = rp[0], Bv = rp[1], Cv = rp[2];
    #pragma unroll 1
    for (int fl = 0; fl < 4; ++fl) {
        v2f pxs = (v2f){A.x,  Bv.y};
        v2f pys = (v2f){A.y,  Cv.x};
        v2f pzs = (v2f){Bv.x, Cv.y};
        v2f wv;
        wv.x = fmaf(A.x,  A.x,  fmaf(A.y,  A.y,  Bv.x * Bv.x));
        wv.y = fmaf(Bv.y, Bv.y, fmaf(Cv.x, Cv.x, Cv.y * Cv.y));
        if (fl < 3) {                    // prefetch next fill (16 recs = 48 float2)
            const float2* np = rp + (fl + 1) * 48;
            A = np[0]; Bv = np[1]; Cv = np[2];
        }
        v2f cacc = (v2f){FLT_BIG, FLT_BIG};
        #pragma unroll
        for (int s = 0; s < 16; ++s) {
            v2f npxs, npys, npzs, nwv;
            if (s < 15) {                // pre-rotate ring for step s+1:
                npxs = rot16v(pxs);      // independent of this step's consumers,
                npys = rot16v(pys);      // scheduler interleaves with the fmas
                npzs = rot16v(pzs);
                nwv  = rot16v(wv);
            }
            do_record_sym(pxs, pys, pzs, wv, qx, qy, qz, qnv, acc, &cacc);
            cacc = rot16v(cacc);         // carries this step's min3 to next host
            if (s < 15) { pxs = npxs; pys = npys; pzs = npzs; wv = nwv; }
        }
        // cacc rotated 16x in-loop == identity -> already at its record's
        // home lane; ring state discarded (next fill repacks from A,Bv,Cv).
        // fold the 4 duplicate rows, relu, stash in LDS.
        cacc.x = fminf(cacc.x, __shfl_xor(cacc.x, 16));
        cacc.x = fminf(cacc.x, __shfl_xor(cacc.x, 32));
        cacc.y = fminf(cacc.y, __shfl_xor(cacc.y, 16));
        cacc.y = fminf(cacc.y, __shfl_xor(cacc.y, 32));
        if (lane < 16) {
            colbuf[wave][fl * 32 + lane * 2]     = fmaxf(0.0f, cacc.x);
            colbuf[wave][fl * 32 + lane * 2 + 1] = fmaxf(0.0f, cacc.y);
        }
    }

    // ---- col epilogue: wave's 128 col-mins -> global atomicMin ----
    {
        unsigned int* py = pmin + 32768 + batch * N_ + 2 * rbase;
        #pragma unroll
        for (int k = 0; k < 2; ++k) {
            int idx = lane * 2 + k;              // 0..127
            float v = colbuf[wave][idx];
            atomicMin(&py[idx], __float_as_uint(v));
        }
    }

    // ---- row epilogue: block combine + relu(qn+min) -> atomicMin ----
    #pragma unroll
    for (int j = 0; j < 8; ++j) red[wave * 512 + lane * 8 + j] = acc[j];
    __syncthreads();
    float m = red[tid];                          // thread t owns query qbase+t
    #pragma unroll
    for (int w = 1; w < 8; ++w) m = fminf(m, red[w * 512 + tid]);
    int gq = qbase + tid;
    float ax = xraw[gq*3+0], ay = xraw[gq*3+1], az = xraw[gq*3+2];
    float qn = fmaf(ax, ax, fmaf(ay, ay, az * az));
    float d2 = fmaxf(0.0f, qn + m);              // relu commutes with min
    atomicMin(&pmin[gq], __float_as_uint(d2));
}

// ---------------- phase 2: sum 65536 per-point d2 -> scalar ----------------
__global__ __launch_bounds__(256) void sum_kernel(
    const unsigned int* __restrict__ pmin, float* __restrict__ out)
{
    int i = blockIdx.x * 256 + threadIdx.x;   // 0..16383, 4 values each
    float4 v = ((const float4*)pmin)[i];      // bits are valid non-neg floats
    float s = v.x + v.y + v.z + v.w;
    #pragma unroll
    for (int off = 32; off > 0; off >>= 1) s += __shfl_xor(s, off);
    if ((threadIdx.x & 63) == 0) atomicAdd(out, s * (1.0f / 32768.0f));
}

// ---------------- fallback (ws too small): round-1 kernel ----------------
__global__ __launch_bounds__(1024) void chamfer_raw_kernel(
    const float* __restrict__ xraw, const float* __restrict__ yraw,
    float* __restrict__ out)
{
    __shared__ float4 red4[16][64];
    const int tid  = threadIdx.x;
    const int wave = tid >> 6;
    const int lane = tid & 63;
    const int blk  = blockIdx.x;
    const bool xdir = (blk < 128);
    const int b    = (blk & 127) >> 5;
    const int qofs = (blk & 31) << 8;
    const float* qraw = xdir ? xraw : yraw;
    const float* oraw = xdir ? yraw : xraw;
    float qx0[4], qx1[4], qx2[4], acc[4];
    #pragma unroll
    for (int q = 0; q < 4; ++q) {
        int gq = b * N_ + qofs + lane*4 + q;
        qx0[q] = qraw[gq*3+0]; qx1[q] = qraw[gq*3+1]; qx2[q] = qraw[gq*3+2];
        acc[q] = FLT_BIG;
    }
    const float* opp = oraw + (size_t)(b * N_ + wave * 512) * 3;
    #pragma unroll 4
    for (int k = 0; k < 512; ++k) {
        float p0 = opp[k*3+0], p1 = opp[k*3+1], p2 = opp[k*3+2];
        float w  = fmaf(p0, p0, fmaf(p1, p1, p2*p2));
        #pragma unroll
        for (int q = 0; q < 4; ++q) {
            float dot = qx0[q]*p0 + qx1[q]*p1 + qx2[q]*p2;
            acc[q] = fminf(acc[q], fmaf(-2.0f, dot, w));
        }
    }
    red4[wave][lane] = make_float4(acc[0], acc[1], acc[2], acc[3]);
    __syncthreads();
    if (tid < 256) {
        const float* red = (const float*)red4;
        float m = red[tid];
        #pragma unroll
        for (int w = 1; w < 16; ++w) m = fminf(m, red[w*256 + tid]);
        int gq = b * N_ + qofs + tid;
        float ax = qraw[gq*3+0], ay = qraw[gq*3+1], az = qraw[gq*3+2];
        float d2 = fmaxf(0.0f, fmaf(ax,ax,fmaf(ay,ay,az*az)) + m);
        #pragma unroll
        for (int off = 32; off > 0; off >>= 1) d2 += __shfl_xor(d2, off);
        if ((tid & 63) == 0) atomicAdd(out, d2 * (1.0f / 32768.0f));
    }
}

extern "C" void kernel_launch(void* const* d_in, const int* in_sizes, int n_in,
                              void* d_out, int out_size, void* d_ws, size_t ws_size,
                              hipStream_t stream)
{
    const float* x = (const float*)d_in[0];
    const float* y = (const float*)d_in[1];
    float* out = (float*)d_out;

    // ws layout: pmin uint[65536] = 256 KB
    const size_t need = (size_t)65536 * 4;
    if (ws_size >= need) {
        unsigned int* pmin = (unsigned int*)d_ws;
        hipMemsetAsync(pmin, 0xFF, need, stream);   // uint-min identity
        hipMemsetAsync(out, 0, 4, stream);
        chamfer_kernel<<<512, 512, 0, stream>>>(x, y, pmin);
        sum_kernel<<<64, 256, 0, stream>>>(pmin, out);
    } else {
        zero_out_kernel<<<1, 1, 0, stream>>>(out);
        chamfer_raw_kernel<<<256, 1024, 0, stream>>>(x, y, out);
    }
}